// Round 23
// baseline (381.359 us; speedup 1.0000x reference)
//
#include <hip/hip_runtime.h>
#include <hip/hip_bf16.h>

#define HDIM 512
#define BDIM 1024
#define DDIM 256
#define MTOT (BDIM * DDIM)

typedef _Float16 half8 __attribute__((ext_vector_type(8)));
typedef float f32x4 __attribute__((ext_vector_type(4)));

__device__ __forceinline__ float ftanh(float x) {
    float e = __expf(2.0f * x);
    float d = e + 1.0f;
    float r;
    asm("v_rcp_f32 %0, %1" : "=v"(r) : "v"(d));
    return 1.0f - 2.0f * r;
}

__device__ __forceinline__ void gl_lds16(const _Float16* src, _Float16* dst) {
    __builtin_amdgcn_global_load_lds((const __attribute__((address_space(1))) void*)src,
                                     (__attribute__((address_space(3))) void*)dst,
                                     16, 0, 0);
}

// K0 (merged): blocks 0..255 = qproj (16 b x 128 g tiles), 256..383 = convert.
// W16 layout: 128 phases of 2048 halves (16 cols x 128 k). Phase p = (c,kq):
// c = p>>2 (16-col group), kq = p&3 (128-k quarter). Granule kb*64 + l
// (kb = 32-k slice 0..3, l = kp*16 + g) holds
//   Wah[c*16 + g][kq*128 + kb*32 + kp*8 .. +8].
// => linear DMA image (1 op/wave/phase: wave w covers kb=w); B-frag read
//    slice kb = granules kb*64 + lane: 64 consecutive granules per wave
//    -> zero bank conflicts (measured R7+).
__global__ __launch_bounds__(256) void k_prep(const float* __restrict__ h_tilde,
                                              const float* __restrict__ c_t,
                                              const float* __restrict__ Waq,
                                              const float* __restrict__ ba,
                                              const float* __restrict__ Wah,
                                              float* __restrict__ qb,
                                              _Float16* __restrict__ W16) {
    __shared__ float qs[16][1024];
    int t = threadIdx.x;
    if (blockIdx.x >= 256) {
        int n = (blockIdx.x - 256) * 256 + t;     // granule id, 32768 total
        int p = n >> 8, r = n & 255;
        int kb = r >> 6, l = r & 63;
        int kp = l >> 4, g = l & 15;
        const float* src = Wah + (size_t)((p >> 2) * 16 + g) * 512
                               + (p & 3) * 128 + kb * 32 + kp * 8;
        float4 v0 = *(const float4*)src;
        float4 v1 = *(const float4*)(src + 4);
        half8 h;
        h[0] = (_Float16)v0.x; h[1] = (_Float16)v0.y; h[2] = (_Float16)v0.z; h[3] = (_Float16)v0.w;
        h[4] = (_Float16)v1.x; h[5] = (_Float16)v1.y; h[6] = (_Float16)v1.z; h[7] = (_Float16)v1.w;
        *(half8*)&W16[(size_t)n * 8] = h;
        return;
    }
    // ---- qproj: block = 16 b x 128 g ----
    int bt = blockIdx.x >> 2, gq = blockIdx.x & 3;
    int b0 = bt * 16;
    #pragma unroll
    for (int i = 0; i < 16; i++) {
        int idx = t + i * 256;
        int row = idx >> 8, k = (idx & 255) * 4;
        float4 v;
        if (k < 512) v = *(const float4*)&h_tilde[(b0 + row) * 512 + k];
        else         v = *(const float4*)&c_t[(b0 + row) * 512 + k - 512];
        *(float4*)&qs[row][k] = v;
    }
    __syncthreads();
    int g = gq * 128 + (t & 127);
    int bh = t >> 7;
    float acc[8] = {0.f, 0.f, 0.f, 0.f, 0.f, 0.f, 0.f, 0.f};
    const float4* wp = (const float4*)&Waq[(size_t)g * 1024];
    #pragma unroll 2
    for (int k4 = 0; k4 < 256; k4++) {
        float4 wv = wp[k4];
        #pragma unroll
        for (int j = 0; j < 8; j++) {
            float4 q = *(const float4*)&qs[bh * 8 + j][k4 * 4];
            acc[j] += q.x * wv.x + q.y * wv.y + q.z * wv.z + q.w * wv.w;
        }
    }
    float bav = ba[g];
    #pragma unroll
    for (int j = 0; j < 8; j++)
        qb[(b0 + bh * 8 + j) * 512 + g] = acc[j] + bav;
}

// K2: R22 structure with DEPTH-5 prefetch through a 6-buffer ring of 4 KB
// phases (128 phases). 64 rows x full N, 4 waves, afr[16] (static indices),
// 4 blocks/CU, fused flash partial softmax + partial e_t.
// body(p): vmcnt(4) [5 in flight -> retires exactly phase p] -> s_barrier ->
// issue p+5 (1 op/wave, into buf (p+5)%6 whose readers finished at p-1) ->
// 4 ds_read + 4 MFMA (literal KQ -> static afr index) -> fold at kq==3.
__global__ __launch_bounds__(256, 4) void k_logits(const float* __restrict__ hist,
                                                   const float* __restrict__ qb,
                                                   const _Float16* __restrict__ W16,
                                                   const float* __restrict__ v_t,
                                                   float* __restrict__ logits,
                                                   float* __restrict__ eparts,
                                                   float* __restrict__ ms) {
    __shared__ _Float16 Wb[6][2048];   // 4 KB each; reused as e_t scratch after loop
    __shared__ float qbs[512];
    __shared__ float vsh[512];
    __shared__ float lsh[64];

    int t = threadIdx.x;
    int w = t >> 6, lane = t & 63, l15 = lane & 15, l4 = lane >> 4;
    int bx = blockIdx.x;
    size_t m_base = (size_t)bx * 64;
    int b = bx >> 2;
    int offp = ((bx >> 3) & 3) * 32;   // multiple of 4 -> kq parity preserved

    qbs[t] = qb[b * 512 + t];
    qbs[t + 256] = qb[b * 512 + 256 + t];
    vsh[t] = v_t[t];
    vsh[t + 256] = v_t[256 + t];

    // prologue: issue DMA for phases 0..4 (1 op each per wave; 5 in flight)
    #pragma unroll
    for (int pp = 0; pp < 5; pp++) {
        const _Float16* wc = W16 + (size_t)((pp + offp) & 127) * 2048;
        gl_lds16(wc + ((size_t)w * 64 + lane) * 8, &Wb[pp][w * 512]);
    }

    // X-load, depth-4 ring (static slots): afr[kb] = X[w*16+l15][kb*32+l4*8..+8]
    half8 afr[16];
    const float* xb = hist + (m_base + w * 16 + l15) * 512 + l4 * 8;
    {
        float4 xr0[4], xr1[4];
        #pragma unroll
        for (int u = 0; u < 4; u++) {
            xr0[u] = *(const float4*)(xb + u * 32);
            xr1[u] = *(const float4*)(xb + u * 32 + 4);
        }
        #pragma unroll
        for (int kb = 0; kb < 16; kb++) {
            const int slot = kb & 3;
            float4 v0 = xr0[slot];
            float4 v1 = xr1[slot];
            if (kb + 4 < 16) {
                xr0[slot] = *(const float4*)(xb + (kb + 4) * 32);
                xr1[slot] = *(const float4*)(xb + (kb + 4) * 32 + 4);
            }
            half8 h;
            h[0] = (_Float16)v0.x; h[1] = (_Float16)v0.y; h[2] = (_Float16)v0.z; h[3] = (_Float16)v0.w;
            h[4] = (_Float16)v1.x; h[5] = (_Float16)v1.y; h[6] = (_Float16)v1.z; h[7] = (_Float16)v1.w;
            afr[kb] = h;
        }
    }

    float S[4] = {0.f, 0.f, 0.f, 0.f};
    f32x4 tac = (f32x4){0.f, 0.f, 0.f, 0.f};

    asm volatile("s_waitcnt lgkmcnt(0)" ::: "memory");  // own qbs/vsh ds_writes

    // KQ is a LITERAL (0..3) -> afr index static. p_ runtime: address math only.
#define PHASE_BODY(P, VMS, ISSUE, KQ)                                          \
    {                                                                          \
        const int p_ = (P);                                                    \
        asm volatile("s_waitcnt vmcnt(" VMS ")" ::: "memory");                 \
        __builtin_amdgcn_s_barrier();                                          \
        if (ISSUE) {                                                           \
            const _Float16* wc_ = W16 + (size_t)((p_ + 5 + offp) & 127) * 2048;\
            _Float16* wd_ = Wb[(p_ + 5) % 6];                                  \
            gl_lds16(wc_ + ((size_t)w * 64 + lane) * 8, &wd_[w * 512]);        \
        }                                                                      \
        const int cc_ = ((p_ + offp) & 127) >> 2;                              \
        const _Float16* bufp_ = &Wb[p_ % 6][lane * 8];                         \
        if ((KQ) == 0) tac = (f32x4){0.f, 0.f, 0.f, 0.f};                      \
        __builtin_amdgcn_s_setprio(1);                                         \
        _Pragma("unroll")                                                      \
        for (int kb_ = 0; kb_ < 4; kb_++) {                                    \
            half8 bf = *(const half8*)(bufp_ + kb_ * 512);                     \
            tac = __builtin_amdgcn_mfma_f32_16x16x32_f16(afr[(KQ) * 4 + kb_], bf, tac, 0, 0, 0); \
        }                                                                      \
        __builtin_amdgcn_s_setprio(0);                                         \
        if ((KQ) == 3) {                                                       \
            float qv = qbs[cc_ * 16 + l15];                                    \
            float vv = vsh[cc_ * 16 + l15];                                    \
            _Pragma("unroll")                                                  \
            for (int j_ = 0; j_ < 4; j_++)                                     \
                S[j_] += ftanh(tac[j_] + qv) * vv;                             \
        }                                                                      \
    }

    for (int q = 0; q < 30; q++) {
        PHASE_BODY(4 * q,     "4", true, 0)
        PHASE_BODY(4 * q + 1, "4", true, 1)
        PHASE_BODY(4 * q + 2, "4", true, 2)
        PHASE_BODY(4 * q + 3, "4", true, 3)
    }
    PHASE_BODY(120, "4", true,  0)
    PHASE_BODY(121, "4", true,  1)
    PHASE_BODY(122, "4", true,  2)   // issues phase 127 (last)
    PHASE_BODY(123, "4", false, 3)
    PHASE_BODY(124, "3", false, 0)
    PHASE_BODY(125, "2", false, 1)
    PHASE_BODY(126, "1", false, 2)
    PHASE_BODY(127, "0", false, 3)
#undef PHASE_BODY

    // ---- logits: reduce over l15; row = w*16 + l4*4 + j ----
    #pragma unroll
    for (int j = 0; j < 4; j++) {
        float s = S[j];
        s += __shfl_xor(s, 1, 64);
        s += __shfl_xor(s, 2, 64);
        s += __shfl_xor(s, 4, 64);
        s += __shfl_xor(s, 8, 64);
        if (l15 == 0) {
            logits[m_base + w * 16 + l4 * 4 + j] = s;
            lsh[w * 16 + l4 * 4 + j] = s;
        }
    }
    __syncthreads();   // lsh complete; all waves past Wb reads (ews-alias safe)

    // ---- block-local softmax stats over the 64 rows ----
    float lv = lsh[lane];
    float mb = lv;
    mb = fmaxf(mb, __shfl_xor(mb, 1, 64));
    mb = fmaxf(mb, __shfl_xor(mb, 2, 64));
    mb = fmaxf(mb, __shfl_xor(mb, 4, 64));
    mb = fmaxf(mb, __shfl_xor(mb, 8, 64));
    mb = fmaxf(mb, __shfl_xor(mb, 16, 64));
    mb = fmaxf(mb, __shfl_xor(mb, 32, 64));
    float eb = __expf(lv - mb);
    float sb = eb;
    sb += __shfl_xor(sb, 1, 64);
    sb += __shfl_xor(sb, 2, 64);
    sb += __shfl_xor(sb, 4, 64);
    sb += __shfl_xor(sb, 8, 64);
    sb += __shfl_xor(sb, 16, 64);
    sb += __shfl_xor(sb, 32, 64);

    // ---- partial e_t from afr: e_blk[h] = sum_rows exp(l-mb) * x16[row][h] ----
    float coef = __expf(lsh[w * 16 + l15] - mb);
    float* ews = (float*)Wb;           // reuse 8 KB of Wb as [4][512] scratch
    #pragma unroll
    for (int kb = 0; kb < 16; kb++) {
        float ep[8];
        half8 x = afr[kb];
        #pragma unroll
        for (int e2 = 0; e2 < 8; e2++) ep[e2] = coef * (float)x[e2];
        #pragma unroll
        for (int e2 = 0; e2 < 8; e2++) {
            ep[e2] += __shfl_xor(ep[e2], 1, 64);
            ep[e2] += __shfl_xor(ep[e2], 2, 64);
            ep[e2] += __shfl_xor(ep[e2], 4, 64);
            ep[e2] += __shfl_xor(ep[e2], 8, 64);
        }
        if (l15 == 0) {
            #pragma unroll
            for (int e2 = 0; e2 < 8; e2++)
                ews[w * 512 + kb * 32 + l4 * 8 + e2] = ep[e2];
        }
    }
    __syncthreads();
    float v0 = ews[t] + ews[512 + t] + ews[1024 + t] + ews[1536 + t];
    float v1 = ews[256 + t] + ews[768 + t] + ews[1280 + t] + ews[1792 + t];
    eparts[(size_t)bx * 512 + t] = v0;
    eparts[(size_t)bx * 512 + 256 + t] = v1;
    if (t == 0) { ms[bx * 2] = mb; ms[bx * 2 + 1] = sb; }
}

// K3: combine 4 block-partials per b (exact flash-combine) -> alpha + e_t.
__global__ __launch_bounds__(256) void k_comb(const float* __restrict__ logits,
                                              const float* __restrict__ eparts,
                                              const float* __restrict__ ms,
                                              float* __restrict__ out) {
    int b = blockIdx.x, t = threadIdx.x;
    float m0 = ms[(4 * b + 0) * 2], s0 = ms[(4 * b + 0) * 2 + 1];
    float m1 = ms[(4 * b + 1) * 2], s1 = ms[(4 * b + 1) * 2 + 1];
    float m2 = ms[(4 * b + 2) * 2], s2 = ms[(4 * b + 2) * 2 + 1];
    float m3 = ms[(4 * b + 3) * 2], s3 = ms[(4 * b + 3) * 2 + 1];
    float m = fmaxf(fmaxf(m0, m1), fmaxf(m2, m3));
    float w0 = __expf(m0 - m), w1 = __expf(m1 - m);
    float w2 = __expf(m2 - m), w3 = __expf(m3 - m);
    float Sb = w0 * s0 + w1 * s1 + w2 * s2 + w3 * s3;
    float l = logits[b * 256 + t];
    out[BDIM * HDIM + b * 256 + t] = __expf(l - m) / Sb;   // alpha
    const float* ep = eparts + (size_t)(4 * b) * 512;
    float a0 = w0 * ep[t] + w1 * ep[512 + t] + w2 * ep[1024 + t] + w3 * ep[1536 + t];
    float a1 = w0 * ep[256 + t] + w1 * ep[768 + t] + w2 * ep[1280 + t] + w3 * ep[1792 + t];
    out[b * 512 + t] = a0 / Sb;                            // e_t
    out[b * 512 + 256 + t] = a1 / Sb;
}

extern "C" void kernel_launch(void* const* d_in, const int* in_sizes, int n_in,
                              void* d_out, int out_size, void* d_ws, size_t ws_size,
                              hipStream_t stream) {
    const float* h_tilde = (const float*)d_in[0];
    const float* c_t     = (const float*)d_in[1];
    const float* hist    = (const float*)d_in[2];
    const float* Waq     = (const float*)d_in[3];
    const float* Wah     = (const float*)d_in[4];
    const float* ba      = (const float*)d_in[5];
    const float* v_t     = (const float*)d_in[6];
    float* out = (float*)d_out;

    char* ws = (char*)d_ws;
    float*    qb     = (float*)ws;                                // 2 MB
    _Float16* W16    = (_Float16*)(ws + (2u << 20));              // 512 KB
    float*    logits = (float*)(ws + (3u << 20));                 // 1 MB
    float*    eparts = (float*)(ws + (4u << 20));                 // 8 MB
    float*    ms     = (float*)(ws + (12u << 20));                // 32 KB

    k_prep<<<384, 256, 0, stream>>>(h_tilde, c_t, Waq, ba, Wah, qb, W16);
    k_logits<<<4096, 256, 0, stream>>>(hist, qb, W16, v_t, logits, eparts, ms);
    k_comb<<<1024, 256, 0, stream>>>(logits, eparts, ms, out);
}

// Round 24
// 335.367 us; speedup vs baseline: 1.1371x; 1.1371x over previous
//
#include <hip/hip_runtime.h>
#include <hip/hip_bf16.h>

#define HDIM 512
#define BDIM 1024
#define DDIM 256
#define MTOT (BDIM * DDIM)

typedef _Float16 half8 __attribute__((ext_vector_type(8)));
typedef float f32x4 __attribute__((ext_vector_type(4)));

__device__ __forceinline__ float ftanh(float x) {
    float e = __expf(2.0f * x);
    float d = e + 1.0f;
    float r;
    asm("v_rcp_f32 %0, %1" : "=v"(r) : "v"(d));
    return 1.0f - 2.0f * r;
}

__device__ __forceinline__ void gl_lds16(const _Float16* src, _Float16* dst) {
    __builtin_amdgcn_global_load_lds((const __attribute__((address_space(1))) void*)src,
                                     (__attribute__((address_space(3))) void*)dst,
                                     16, 0, 0);
}

// K0 (merged): blocks 0..255 = qproj (16 b x 128 g tiles), 256..383 = convert.
// W16 PHASE-major: 64 phases of 4096 halves (16 cols x 256 k). Within phase
// p=(c,kh): granule kb*64 + kp*16 + g holds Wah[c*16+g][kh*256 + kb*32 + kp*8].
// B-frag for lane l = granule kb*64 + l -> 1024 consecutive bytes per wave
// (measured 0 bank conflicts).
__global__ __launch_bounds__(256) void k_prep(const float* __restrict__ h_tilde,
                                              const float* __restrict__ c_t,
                                              const float* __restrict__ Waq,
                                              const float* __restrict__ ba,
                                              const float* __restrict__ Wah,
                                              float* __restrict__ qb,
                                              _Float16* __restrict__ W16) {
    __shared__ float qs[16][1024];
    int t = threadIdx.x;
    if (blockIdx.x >= 256) {
        int n = (blockIdx.x - 256) * 256 + t;     // granule id, 32768 total
        int p = n >> 9, r = n & 511;
        int kb = r >> 6, kp = (r >> 4) & 3, g = r & 15;
        int c = p >> 1, kh = p & 1;
        const float* src = Wah + (size_t)(c * 16 + g) * 512 + kh * 256 + kb * 32 + kp * 8;
        float4 v0 = *(const float4*)src;
        float4 v1 = *(const float4*)(src + 4);
        half8 h;
        h[0] = (_Float16)v0.x; h[1] = (_Float16)v0.y; h[2] = (_Float16)v0.z; h[3] = (_Float16)v0.w;
        h[4] = (_Float16)v1.x; h[5] = (_Float16)v1.y; h[6] = (_Float16)v1.z; h[7] = (_Float16)v1.w;
        *(half8*)&W16[(size_t)n * 8] = h;
        return;
    }
    // ---- qproj: block = 16 b x 128 g ----
    int bt = blockIdx.x >> 2, gq = blockIdx.x & 3;
    int b0 = bt * 16;
    #pragma unroll
    for (int i = 0; i < 16; i++) {
        int idx = t + i * 256;
        int row = idx >> 8, k = (idx & 255) * 4;
        float4 v;
        if (k < 512) v = *(const float4*)&h_tilde[(b0 + row) * 512 + k];
        else         v = *(const float4*)&c_t[(b0 + row) * 512 + k - 512];
        *(float4*)&qs[row][k] = v;
    }
    __syncthreads();
    int g = gq * 128 + (t & 127);
    int bh = t >> 7;
    float acc[8] = {0.f, 0.f, 0.f, 0.f, 0.f, 0.f, 0.f, 0.f};
    const float4* wp = (const float4*)&Waq[(size_t)g * 1024];
    #pragma unroll 2
    for (int k4 = 0; k4 < 256; k4++) {
        float4 wv = wp[k4];
        #pragma unroll
        for (int j = 0; j < 8; j++) {
            float4 q = *(const float4*)&qs[bh * 8 + j][k4 * 4];
            acc[j] += q.x * wv.x + q.y * wv.y + q.z * wv.z + q.w * wv.w;
        }
    }
    float bav = ba[g];
    #pragma unroll
    for (int j = 0; j < 8; j++)
        qb[(b0 + bh * 8 + j) * 512 + g] = acc[j] + bav;
}

// K2: converged configuration (R22): 64 rows x full N, 4 waves, afr[16]
// (64 AGPR, static indices), 4 blocks/CU, fused flash partial softmax +
// partial e_t. 4-buffer ring, DEPTH-3 prefetch: body(p): vmcnt(4) [phase p
// complete; p+1,p+2 in flight] -> s_barrier -> issue p+3 (into buffer
// (p-1)&3, readers past the barrier) -> 8 ds_read + 8 MFMA -> fold on odd
// phase. Literal KH=0/1 keeps afr[] indices compile-time (rule #20).
__global__ __launch_bounds__(256, 4) void k_logits(const float* __restrict__ hist,
                                                   const float* __restrict__ qb,
                                                   const _Float16* __restrict__ W16,
                                                   const float* __restrict__ v_t,
                                                   float* __restrict__ logits,
                                                   float* __restrict__ eparts,
                                                   float* __restrict__ ms) {
    __shared__ _Float16 Wb[4][4096];   // 8 KB each; reused as e_t scratch after loop
    __shared__ float qbs[512];
    __shared__ float vsh[512];
    __shared__ float lsh[64];

    int t = threadIdx.x;
    int w = t >> 6, lane = t & 63, l15 = lane & 15, l4 = lane >> 4;
    int bx = blockIdx.x;
    size_t m_base = (size_t)bx * 64;
    int b = bx >> 2;
    int offp = ((bx >> 3) & 3) * 16;   // EVEN stagger -> kh parity preserved

    qbs[t] = qb[b * 512 + t];
    qbs[t + 256] = qb[b * 512 + 256 + t];
    vsh[t] = v_t[t];
    vsh[t + 256] = v_t[256 + t];

    // prologue: issue DMA for phases 0,1,2 (2 ops each per wave; 6 in flight)
    #pragma unroll
    for (int pp = 0; pp < 3; pp++) {
        const _Float16* wc = W16 + (size_t)((pp + offp) & 63) * 4096;
        #pragma unroll
        for (int sg = 0; sg < 2; sg++)
            gl_lds16(wc + ((size_t)(w * 2 + sg) * 64 + lane) * 8,
                     &Wb[pp][(w * 2 + sg) * 512]);
    }

    // X-load, depth-4 ring (static slots): afr[kb] = X[w*16+l15][kb*32+l4*8..+8]
    half8 afr[16];
    const float* xb = hist + (m_base + w * 16 + l15) * 512 + l4 * 8;
    {
        float4 xr0[4], xr1[4];
        #pragma unroll
        for (int u = 0; u < 4; u++) {
            xr0[u] = *(const float4*)(xb + u * 32);
            xr1[u] = *(const float4*)(xb + u * 32 + 4);
        }
        #pragma unroll
        for (int kb = 0; kb < 16; kb++) {
            const int slot = kb & 3;
            float4 v0 = xr0[slot];
            float4 v1 = xr1[slot];
            if (kb + 4 < 16) {
                xr0[slot] = *(const float4*)(xb + (kb + 4) * 32);
                xr1[slot] = *(const float4*)(xb + (kb + 4) * 32 + 4);
            }
            half8 h;
            h[0] = (_Float16)v0.x; h[1] = (_Float16)v0.y; h[2] = (_Float16)v0.z; h[3] = (_Float16)v0.w;
            h[4] = (_Float16)v1.x; h[5] = (_Float16)v1.y; h[6] = (_Float16)v1.z; h[7] = (_Float16)v1.w;
            afr[kb] = h;
        }
    }

    float S[4] = {0.f, 0.f, 0.f, 0.f};
    f32x4 tac = (f32x4){0.f, 0.f, 0.f, 0.f};

    asm volatile("s_waitcnt lgkmcnt(0)" ::: "memory");  // own qbs/vsh ds_writes

    // KH is a LITERAL (0/1) -> afr index static. p_ runtime: address math only.
#define PHASE_BODY(P, VMS, ISSUE, KH)                                          \
    {                                                                          \
        const int p_ = (P);                                                    \
        asm volatile("s_waitcnt vmcnt(" VMS ")" ::: "memory");                 \
        __builtin_amdgcn_s_barrier();                                          \
        if (ISSUE) {                                                           \
            const _Float16* wc_ = W16 + (size_t)((p_ + 3 + offp) & 63) * 4096; \
            _Float16* wd_ = Wb[(p_ + 3) & 3];                                  \
            _Pragma("unroll")                                                  \
            for (int sg_ = 0; sg_ < 2; sg_++)                                  \
                gl_lds16(wc_ + ((size_t)(w * 2 + sg_) * 64 + lane) * 8,        \
                         &wd_[(w * 2 + sg_) * 512]);                           \
        }                                                                      \
        const int cc_ = ((p_ + offp) & 63) >> 1;                               \
        const _Float16* bufp_ = &Wb[p_ & 3][lane * 8];                         \
        if ((KH) == 0) tac = (f32x4){0.f, 0.f, 0.f, 0.f};                      \
        __builtin_amdgcn_s_setprio(1);                                         \
        _Pragma("unroll")                                                      \
        for (int kb_ = 0; kb_ < 8; kb_++) {                                    \
            half8 bf = *(const half8*)(bufp_ + kb_ * 512);                     \
            tac = __builtin_amdgcn_mfma_f32_16x16x32_f16(afr[(KH) * 8 + kb_], bf, tac, 0, 0, 0); \
        }                                                                      \
        __builtin_amdgcn_s_setprio(0);                                         \
        if ((KH) == 1) {                                                       \
            float qv = qbs[cc_ * 16 + l15];                                    \
            float vv = vsh[cc_ * 16 + l15];                                    \
            _Pragma("unroll")                                                  \
            for (int j_ = 0; j_ < 4; j_++)                                     \
                S[j_] += ftanh(tac[j_] + qv) * vv;                             \
        }                                                                      \
    }

    for (int q = 0; q < 30; q++) {
        PHASE_BODY(2 * q,     "4", true, 0)
        PHASE_BODY(2 * q + 1, "4", true, 1)
    }
    PHASE_BODY(60, "4", true,  0)   // issues phase 63 (last)
    PHASE_BODY(61, "4", false, 1)
    PHASE_BODY(62, "2", false, 0)
    PHASE_BODY(63, "0", false, 1)
#undef PHASE_BODY

    // ---- logits: reduce over l15; row = w*16 + l4*4 + j ----
    #pragma unroll
    for (int j = 0; j < 4; j++) {
        float s = S[j];
        s += __shfl_xor(s, 1, 64);
        s += __shfl_xor(s, 2, 64);
        s += __shfl_xor(s, 4, 64);
        s += __shfl_xor(s, 8, 64);
        if (l15 == 0) {
            logits[m_base + w * 16 + l4 * 4 + j] = s;
            lsh[w * 16 + l4 * 4 + j] = s;
        }
    }
    __syncthreads();   // lsh complete; all waves past Wb reads (ews-alias safe)

    // ---- block-local softmax stats over the 64 rows ----
    float lv = lsh[lane];
    float mb = lv;
    mb = fmaxf(mb, __shfl_xor(mb, 1, 64));
    mb = fmaxf(mb, __shfl_xor(mb, 2, 64));
    mb = fmaxf(mb, __shfl_xor(mb, 4, 64));
    mb = fmaxf(mb, __shfl_xor(mb, 8, 64));
    mb = fmaxf(mb, __shfl_xor(mb, 16, 64));
    mb = fmaxf(mb, __shfl_xor(mb, 32, 64));
    float eb = __expf(lv - mb);
    float sb = eb;
    sb += __shfl_xor(sb, 1, 64);
    sb += __shfl_xor(sb, 2, 64);
    sb += __shfl_xor(sb, 4, 64);
    sb += __shfl_xor(sb, 8, 64);
    sb += __shfl_xor(sb, 16, 64);
    sb += __shfl_xor(sb, 32, 64);

    // ---- partial e_t from afr: e_blk[h] = sum_rows exp(l-mb) * x16[row][h] ----
    float coef = __expf(lsh[w * 16 + l15] - mb);
    float* ews = (float*)Wb;           // reuse 8 KB of Wb as [4][512] scratch
    #pragma unroll
    for (int kb = 0; kb < 16; kb++) {
        float ep[8];
        half8 x = afr[kb];
        #pragma unroll
        for (int e2 = 0; e2 < 8; e2++) ep[e2] = coef * (float)x[e2];
        #pragma unroll
        for (int e2 = 0; e2 < 8; e2++) {
            ep[e2] += __shfl_xor(ep[e2], 1, 64);
            ep[e2] += __shfl_xor(ep[e2], 2, 64);
            ep[e2] += __shfl_xor(ep[e2], 4, 64);
            ep[e2] += __shfl_xor(ep[e2], 8, 64);
        }
        if (l15 == 0) {
            #pragma unroll
            for (int e2 = 0; e2 < 8; e2++)
                ews[w * 512 + kb * 32 + l4 * 8 + e2] = ep[e2];
        }
    }
    __syncthreads();
    float v0 = ews[t] + ews[512 + t] + ews[1024 + t] + ews[1536 + t];
    float v1 = ews[256 + t] + ews[768 + t] + ews[1280 + t] + ews[1792 + t];
    eparts[(size_t)bx * 512 + t] = v0;
    eparts[(size_t)bx * 512 + 256 + t] = v1;
    if (t == 0) { ms[bx * 2] = mb; ms[bx * 2 + 1] = sb; }
}

// K3: combine 4 block-partials per b (exact flash-combine) -> alpha + e_t.
__global__ __launch_bounds__(256) void k_comb(const float* __restrict__ logits,
                                              const float* __restrict__ eparts,
                                              const float* __restrict__ ms,
                                              float* __restrict__ out) {
    int b = blockIdx.x, t = threadIdx.x;
    float m0 = ms[(4 * b + 0) * 2], s0 = ms[(4 * b + 0) * 2 + 1];
    float m1 = ms[(4 * b + 1) * 2], s1 = ms[(4 * b + 1) * 2 + 1];
    float m2 = ms[(4 * b + 2) * 2], s2 = ms[(4 * b + 2) * 2 + 1];
    float m3 = ms[(4 * b + 3) * 2], s3 = ms[(4 * b + 3) * 2 + 1];
    float m = fmaxf(fmaxf(m0, m1), fmaxf(m2, m3));
    float w0 = __expf(m0 - m), w1 = __expf(m1 - m);
    float w2 = __expf(m2 - m), w3 = __expf(m3 - m);
    float Sb = w0 * s0 + w1 * s1 + w2 * s2 + w3 * s3;
    float l = logits[b * 256 + t];
    out[BDIM * HDIM + b * 256 + t] = __expf(l - m) / Sb;   // alpha
    const float* ep = eparts + (size_t)(4 * b) * 512;
    float a0 = w0 * ep[t] + w1 * ep[512 + t] + w2 * ep[1024 + t] + w3 * ep[1536 + t];
    float a1 = w0 * ep[256 + t] + w1 * ep[768 + t] + w2 * ep[1280 + t] + w3 * ep[1792 + t];
    out[b * 512 + t] = a0 / Sb;                            // e_t
    out[b * 512 + 256 + t] = a1 / Sb;
}

extern "C" void kernel_launch(void* const* d_in, const int* in_sizes, int n_in,
                              void* d_out, int out_size, void* d_ws, size_t ws_size,
                              hipStream_t stream) {
    const float* h_tilde = (const float*)d_in[0];
    const float* c_t     = (const float*)d_in[1];
    const float* hist    = (const float*)d_in[2];
    const float* Waq     = (const float*)d_in[3];
    const float* Wah     = (const float*)d_in[4];
    const float* ba      = (const float*)d_in[5];
    const float* v_t     = (const float*)d_in[6];
    float* out = (float*)d_out;

    char* ws = (char*)d_ws;
    float*    qb     = (float*)ws;                                // 2 MB
    _Float16* W16    = (_Float16*)(ws + (2u << 20));              // 512 KB
    float*    logits = (float*)(ws + (3u << 20));                 // 1 MB
    float*    eparts = (float*)(ws + (4u << 20));                 // 8 MB
    float*    ms     = (float*)(ws + (12u << 20));                // 32 KB

    k_prep<<<384, 256, 0, stream>>>(h_tilde, c_t, Waq, ba, Wah, qb, W16);
    k_logits<<<4096, 256, 0, stream>>>(hist, qb, W16, v_t, logits, eparts, ms);
    k_comb<<<1024, 256, 0, stream>>>(logits, eparts, ms, out);
}